// Round 4
// baseline (1040.766 us; speedup 1.0000x reference)
//
#include <hip/hip_runtime.h>
#include <math.h>

#define BIGI (1 << 30)

// ---- workspace layout (4-byte units) ----
#define MM_OFF   0         // 64 images x 4 ints
#define P2T_OFF  256       // pos2T[k=256][r=64]  (r = b*16+t)
#define H1T_OFF  16640     // h1T[(b*256+u)*16 + t]  (layer-0 h history)
#define WT_OFF   33024     // whhT bf16-packed: [(L*1024+c)*128 + k2] u32
// end: 295168 dwords = 1.18 MB

// ---- output layout (floats) ----
#define OUT_DELTAS 0       // (4,5,4)
#define OUT_PBB    80      // (4,5,4)
#define OUT_LOC    160     // (4,5,2)
#define OUT_SCL    200     // (4,5,2)
#define OUT_MF     240     // (4,16,256)
#define OUT_CONF   16624   // (4,5)
#define OUT_BBOX   16644   // (4,16,4)

// ---- LDS layout for chain kernels (floats) ----
#define OFF_XG   0         // xg[t=16][c=1024]
#define OFF_HB   16384     // hbuf[256]
#define OFF_GT   16640     // gates[1024]
#define CHAIN_SMEM 17664   // 70.7 KB

__device__ __forceinline__ float sigmoidf_(float x) { return 1.0f / (1.0f + expf(-x)); }
__device__ __forceinline__ float blo(unsigned int w) { return __uint_as_float(w << 16); }
__device__ __forceinline__ float bhi(unsigned int w) { return __uint_as_float(w & 0xFFFF0000u); }
__device__ __forceinline__ unsigned short f2bf(float f) {
    unsigned int u = __float_as_uint(f);
    return (unsigned short)((u + 0x7FFFu + ((u >> 16) & 1u)) >> 16);  // RNE
}

// ---------------- kernel 1: init minmax sentinels ----------------
__global__ void k_init(int* ws) {
    int tid = threadIdx.x;
    ws[MM_OFF + tid] = (tid & 1) ? -1 : BIGI;
}

// ---------------- kernel 2: per-image mask min/max ----------------
__global__ __launch_bounds__(256) void k_minmax(const float4* __restrict__ pred,
                                                int* __restrict__ mm) {
    int img = blockIdx.x >> 5;
    int chunk = blockIdx.x & 31;
    int tid = threadIdx.x;
    int base = img * 262144 + chunk * 8192 + tid;
    int xmn = BIGI, xmx = -1, ymn = BIGI, ymx = -1;
#pragma unroll 4
    for (int i = 0; i < 32; ++i) {
        int idx4 = base + i * 256;
        float4 v = pred[idx4];
        int x = (idx4 << 2) & 1023;
        int y = (idx4 >> 8) & 1023;
        bool m0 = v.x > 0.5f, m1 = v.y > 0.5f, m2 = v.z > 0.5f, m3 = v.w > 0.5f;
        int cmn = m0 ? x : (m1 ? x + 1 : (m2 ? x + 2 : (m3 ? x + 3 : BIGI)));
        int cmx = m3 ? x + 3 : (m2 ? x + 2 : (m1 ? x + 1 : (m0 ? x : -1)));
        xmn = min(xmn, cmn);
        xmx = max(xmx, cmx);
        if (m0 | m1 | m2 | m3) { ymn = min(ymn, y); ymx = max(ymx, y); }
    }
    for (int off = 32; off > 0; off >>= 1) {
        xmn = min(xmn, __shfl_down(xmn, off));
        xmx = max(xmx, __shfl_down(xmx, off));
        ymn = min(ymn, __shfl_down(ymn, off));
        ymx = max(ymx, __shfl_down(ymx, off));
    }
    __shared__ int red[4][4];
    int wave = tid >> 6;
    if ((tid & 63) == 0) { red[0][wave] = xmn; red[1][wave] = xmx; red[2][wave] = ymn; red[3][wave] = ymx; }
    __syncthreads();
    if (tid == 0) {
        xmn = min(min(red[0][0], red[0][1]), min(red[0][2], red[0][3]));
        xmx = max(max(red[1][0], red[1][1]), max(red[1][2], red[1][3]));
        ymn = min(min(red[2][0], red[2][1]), min(red[2][2], red[2][3]));
        ymx = max(max(red[3][0], red[3][1]), max(red[3][2], red[3][3]));
        atomicMin(&mm[img * 4 + 0], xmn);
        atomicMax(&mm[img * 4 + 1], xmx);
        atomicMin(&mm[img * 4 + 2], ymn);
        atomicMax(&mm[img * 4 + 3], ymx);
    }
}

__device__ __forceinline__ void bbox_of(const int* mm, int img, float v[4]) {
    int xmn = mm[img * 4 + 0], xmx = mm[img * 4 + 1];
    int ymn = mm[img * 4 + 2], ymx = mm[img * 4 + 3];
    if (xmx >= 0) {
        v[0] = (float)(xmn + xmx) * (0.5f / 1024.0f);
        v[1] = (float)(ymn + ymx) * (0.5f / 1024.0f);
        v[2] = (float)(xmx - xmn) * (1.0f / 1024.0f);
        v[3] = (float)(ymx - ymn) * (1.0f / 1024.0f);
    } else { v[0] = 0.5f; v[1] = 0.5f; v[2] = 0.1f; v[3] = 0.1f; }
}

// ---------------- kernel 3: prep — whh transpose->bf16 + pos-MLP ----------------
// wgs 0..7: transpose (L = w>>2, col group = w&3). wgs 8..23: pos MLP, 4 images each.
__global__ __launch_bounds__(256) void k_prep(
    const float* __restrict__ whh0, const float* __restrict__ whh1,
    const float* __restrict__ pe_w1, const float* __restrict__ pe_b1,
    const float* __restrict__ pe_w2, const float* __restrict__ pe_b2,
    float* __restrict__ out, int* __restrict__ wsi, float* __restrict__ wsf) {
    int w = blockIdx.x, tid = threadIdx.x;
    if (w < 8) {
        int L = w >> 2;
        int c = (w & 3) * 256 + tid;
        const float* whh = L ? whh1 : whh0;
        unsigned int* dst = (unsigned int*)wsf + WT_OFF + (L * 1024 + c) * 128;
#pragma unroll 4
        for (int k2 = 0; k2 < 128; ++k2) {
            unsigned int lo = f2bf(whh[(2 * k2) * 1024 + c]);
            unsigned int hi = f2bf(whh[(2 * k2 + 1) * 1024 + c]);
            dst[k2] = (hi << 16) | lo;
        }
        return;
    }
    // pos MLP for images w4..w4+3
    __shared__ float sb[4 * 4];        // bboxes
    __shared__ float sp1[4 * 256];     // pos1
    int w4 = (w - 8) * 4;
    if (tid < 4) {
        float v[4];
        bbox_of(wsi + MM_OFF, w4 + tid, v);
        sb[tid * 4 + 0] = v[0]; sb[tid * 4 + 1] = v[1];
        sb[tid * 4 + 2] = v[2]; sb[tid * 4 + 3] = v[3];
        out[OUT_BBOX + (w4 + tid) * 4 + 0] = v[0];
        out[OUT_BBOX + (w4 + tid) * 4 + 1] = v[1];
        out[OUT_BBOX + (w4 + tid) * 4 + 2] = v[2];
        out[OUT_BBOX + (w4 + tid) * 4 + 3] = v[3];
    }
    __syncthreads();
    {
        float wv0 = pe_w1[tid], wv1 = pe_w1[256 + tid];
        float wv2 = pe_w1[512 + tid], wv3 = pe_w1[768 + tid];
        float bb = pe_b1[tid];
#pragma unroll
        for (int i = 0; i < 4; ++i) {
            const float* bp = sb + i * 4;
            float v = bp[0] * wv0 + bp[1] * wv1 + bp[2] * wv2 + bp[3] * wv3 + bb;
            sp1[i * 256 + tid] = fmaxf(v, 0.0f);
        }
    }
    __syncthreads();
    {
        float a0 = pe_b2[tid], a1 = a0, a2 = a0, a3 = a0;
#pragma unroll 4
        for (int k = 0; k < 256; ++k) {
            float wv = pe_w2[k * 256 + tid];
            a0 += sp1[0 * 256 + k] * wv;
            a1 += sp1[1 * 256 + k] * wv;
            a2 += sp1[2 * 256 + k] * wv;
            a3 += sp1[3 * 256 + k] * wv;
        }
        float* p = wsf + P2T_OFF + tid * 64 + w4;   // pos2T[k=tid][r=w4+i]
        p[0] = fmaxf(a0, 0.0f);
        p[1] = fmaxf(a1, 0.0f);
        p[2] = fmaxf(a2, 0.0f);
        p[3] = fmaxf(a3, 0.0f);
    }
}

// ---- shared recurrence body: xg precompute (SGPR-broadcast x) + 16 LSTM steps ----
// One wg per batch (1024 threads, c = tid = global gate col).
template <int LAYER>
__device__ __forceinline__ void lstm_layer(
    int b, int tid, float* smem,
    const float* __restrict__ xsrc,     // LAYER0: pos2T[k*64+b*16+t]; LAYER1: h1T[(b*256+k)*16+t]
    const float* __restrict__ wih,
    const float* __restrict__ bih, const float* __restrict__ bhh,
    const unsigned int* __restrict__ whhT,  // [(c)*128 + k2] for this layer
    float* __restrict__ h1T,            // LAYER0: write h history; LAYER1: null
    float* __restrict__ out) {
    const int c = tid;
    // ---- xg[t][c] = bih[c]+bhh[c] + sum_k x[t][k]*wih[k][c] ----
    {
        float acc[16];
        float bias = bih[c] + bhh[c];
#pragma unroll
        for (int t = 0; t < 16; ++t) acc[t] = bias;
        for (int k = 0; k < 256; ++k) {
            float wv = wih[k * 1024 + c];
            const float* xr = (LAYER == 0) ? (xsrc + k * 64 + b * 16)
                                           : (xsrc + (b * 256 + k) * 16);
#pragma unroll
            for (int t = 0; t < 16; ++t) acc[t] += xr[t] * wv;  // xr[t] wave-uniform -> s_load
        }
#pragma unroll
        for (int t = 0; t < 16; ++t) smem[OFF_XG + t * 1024 + c] = acc[t];
    }
    __syncthreads();
    // ---- 16 recurrent steps ----
    float cst = 0.0f;
    const float4* hb4 = (const float4*)(smem + OFF_HB);
    const uint4* Wc = (const uint4*)(whhT + c * 128);
    for (int t = 0; t < 16; ++t) {
        float g = smem[OFF_XG + t * 1024 + c];
        if (t > 0) {
#pragma unroll 8
            for (int j = 0; j < 32; ++j) {
                uint4 W4 = Wc[j];
                float4 ha = hb4[2 * j];
                float4 hbv = hb4[2 * j + 1];
                g += blo(W4.x) * ha.x + bhi(W4.x) * ha.y
                   + blo(W4.y) * ha.z + bhi(W4.y) * ha.w
                   + blo(W4.z) * hbv.x + bhi(W4.z) * hbv.y
                   + blo(W4.w) * hbv.z + bhi(W4.w) * hbv.w;
            }
        }
        smem[OFF_GT + c] = g;
        __syncthreads();
        if (tid < 256) {
            int u = tid;
            float i_ = sigmoidf_(smem[OFF_GT + u]);
            float f_ = sigmoidf_(smem[OFF_GT + 256 + u]);
            float gg = tanhf(smem[OFF_GT + 512 + u]);
            float o_ = sigmoidf_(smem[OFF_GT + 768 + u]);
            cst = f_ * cst + i_ * gg;
            float h = o_ * tanhf(cst);
            smem[OFF_HB + u] = h;
            if (LAYER == 0) h1T[(b * 256 + u) * 16 + t] = h;
            else out[OUT_MF + (b * 16 + t) * 256 + u] = h;
        }
        __syncthreads();
    }
}

// ---------------- kernel 4a: layer-0 chain (4 wgs, one per batch) ----------------
__global__ __launch_bounds__(1024, 4) void k_chainA(
    const float* __restrict__ wih0, const float* __restrict__ bih0,
    const float* __restrict__ bhh0,
    float* __restrict__ out, int* __restrict__ wsi, float* __restrict__ wsf) {
    __shared__ float smem[CHAIN_SMEM];
    int b = blockIdx.x, tid = threadIdx.x;
    const unsigned int* whhT = (const unsigned int*)wsf + WT_OFF;  // layer 0
    lstm_layer<0>(b, tid, smem, wsf + P2T_OFF, wih0, bih0, bhh0, whhT,
                  wsf + H1T_OFF, out);
}

// ---------------- kernel 4b: layer-1 chain + heads ----------------
__global__ __launch_bounds__(1024, 4) void k_chainB(
    const float* __restrict__ wih1, const float* __restrict__ bih1,
    const float* __restrict__ bhh1,
    const float* __restrict__ mp_w1, const float* __restrict__ mp_b1,
    const float* __restrict__ mp_w2, const float* __restrict__ mp_b2,
    const float* __restrict__ mp_w3, const float* __restrict__ mp_b3,
    const float* __restrict__ cf_w1, const float* __restrict__ cf_b1,
    const float* __restrict__ cf_w2, const float* __restrict__ cf_b2,
    float* __restrict__ out, int* __restrict__ wsi, float* __restrict__ wsf) {
    __shared__ float smem[CHAIN_SMEM];
    int b = blockIdx.x, tid = threadIdx.x;
    const unsigned int* whhT = (const unsigned int*)wsf + WT_OFF + 1024 * 128;  // layer 1
    lstm_layer<1>(b, tid, smem, wsf + H1T_OFF, wih1, bih1, bhh1, whhT,
                  nullptr, out);
    // ---- heads for batch b; last_hidden = smem[OFF_HB..+256) ----
    float* x1 = smem;          // reuse xg area
    float* c1 = smem + 256;
    float* x2 = smem + 384;
    float* dl = smem + 512;
    const float* lh = smem + OFF_HB;
    if (tid < 256) {
        float a = mp_b1[tid];
#pragma unroll 4
        for (int k = 0; k < 256; ++k) a += lh[k] * mp_w1[k * 256 + tid];
        x1[tid] = fmaxf(a, 0.0f);
    } else if (tid < 384) {
        int cc = tid - 256;
        float a = cf_b1[cc];
#pragma unroll 4
        for (int k = 0; k < 256; ++k) a += lh[k] * cf_w1[k * 128 + cc];
        c1[cc] = fmaxf(a, 0.0f);
    }
    __syncthreads();
    if (tid < 128) {
        float a = mp_b2[tid];
#pragma unroll 4
        for (int k = 0; k < 256; ++k) a += x1[k] * mp_w2[k * 128 + tid];
        x2[tid] = fmaxf(a, 0.0f);
    } else if (tid < 133) {
        int j = tid - 128;
        float a = cf_b2[j];
#pragma unroll 4
        for (int k = 0; k < 128; ++k) a += c1[k] * cf_w2[k * 5 + j];
        out[OUT_CONF + b * 5 + j] = sigmoidf_(a);
    }
    __syncthreads();
    if (tid < 20) {
        float a = mp_b3[tid];
#pragma unroll 4
        for (int k = 0; k < 128; ++k) a += x2[k] * mp_w3[k * 20 + tid];
        dl[tid] = a;
        out[OUT_DELTAS + b * 20 + tid] = a;
    }
    __syncthreads();
    if (tid < 4) {
        float v[4];
        bbox_of(wsi + MM_OFF, b * 16 + 15, v);
        float a = v[tid];
        for (int h = 0; h < 5; ++h) {
            a += dl[h * 4 + tid];
            out[OUT_PBB + b * 20 + h * 4 + tid] = a;
            if (tid < 2) out[OUT_LOC + b * 10 + h * 2 + tid] = a;
            else out[OUT_SCL + b * 10 + h * 2 + (tid - 2)] = a;
        }
    }
}

extern "C" void kernel_launch(void* const* d_in, const int* in_sizes, int n_in,
                              void* d_out, int out_size, void* d_ws, size_t ws_size,
                              hipStream_t stream) {
    (void)in_sizes; (void)n_in; (void)out_size; (void)ws_size;
    const float* pred = (const float*)d_in[1];  // d_in[0] = features (unused)
    const float* pe_w1 = (const float*)d_in[2];
    const float* pe_b1 = (const float*)d_in[3];
    const float* pe_w2 = (const float*)d_in[4];
    const float* pe_b2 = (const float*)d_in[5];
    const float* wih0 = (const float*)d_in[6];
    const float* whh0 = (const float*)d_in[7];
    const float* bih0 = (const float*)d_in[8];
    const float* bhh0 = (const float*)d_in[9];
    const float* wih1 = (const float*)d_in[10];
    const float* whh1 = (const float*)d_in[11];
    const float* bih1 = (const float*)d_in[12];
    const float* bhh1 = (const float*)d_in[13];
    const float* mp_w1 = (const float*)d_in[14];
    const float* mp_b1 = (const float*)d_in[15];
    const float* mp_w2 = (const float*)d_in[16];
    const float* mp_b2 = (const float*)d_in[17];
    const float* mp_w3 = (const float*)d_in[18];
    const float* mp_b3 = (const float*)d_in[19];
    const float* cf_w1 = (const float*)d_in[20];
    const float* cf_b1 = (const float*)d_in[21];
    const float* cf_w2 = (const float*)d_in[22];
    const float* cf_b2 = (const float*)d_in[23];
    float* out = (float*)d_out;
    int* wsi = (int*)d_ws;
    float* wsf = (float*)d_ws;

    hipLaunchKernelGGL(k_init, dim3(1), dim3(256), 0, stream, wsi);
    hipLaunchKernelGGL(k_minmax, dim3(64 * 32), dim3(256), 0, stream,
                       (const float4*)pred, wsi + MM_OFF);
    hipLaunchKernelGGL(k_prep, dim3(24), dim3(256), 0, stream,
                       whh0, whh1, pe_w1, pe_b1, pe_w2, pe_b2, out, wsi, wsf);
    hipLaunchKernelGGL(k_chainA, dim3(4), dim3(1024), 0, stream,
                       wih0, bih0, bhh0, out, wsi, wsf);
    hipLaunchKernelGGL(k_chainB, dim3(4), dim3(1024), 0, stream,
                       wih1, bih1, bhh1,
                       mp_w1, mp_b1, mp_w2, mp_b2, mp_w3, mp_b3,
                       cf_w1, cf_b1, cf_w2, cf_b2, out, wsi, wsf);
}